// Round 14
// baseline (91.584 us; speedup 1.0000x reference)
//
#include <hip/hip_runtime.h>
#include <hip/hip_bf16.h>
#include <stdint.h>

#define S    2304
#define CHN  256
#define BATCH 4
#define NKEYS 1152                  // keys per half (in-block 2-way split)
#define QS   0.09016844005556021f   // (1/16) * log2(e)

typedef __attribute__((ext_vector_type(8))) short bf16x8;
typedef __attribute__((ext_vector_type(4))) short bf16x4;
typedef __attribute__((ext_vector_type(4))) float f32x4;
typedef __attribute__((ext_vector_type(4))) uint32_t u32x4;
typedef __attribute__((ext_vector_type(4))) unsigned short u16x4;
typedef unsigned short u16;

#define AS1 __attribute__((address_space(1)))
#define AS3 __attribute__((address_space(3)))
#define GLDS(gptr, lptr) __builtin_amdgcn_global_load_lds((const AS1 void*)(gptr), (AS3 void*)(lptr), 16, 0, 0)

__device__ __forceinline__ u16 f2bf(float f) {
  union { float f; uint32_t u; } v; v.f = f;
  uint32_t u = v.u;
  u += 0x7fffu + ((u >> 16) & 1u);
  return (u16)(u >> 16);
}
__device__ __forceinline__ float bf2f(u16 h) {
  union { uint32_t u; float f; } v; v.u = ((uint32_t)h) << 16;
  return v.f;
}
__device__ __forceinline__ uint32_t pk_bf16(float a, float b) {
  union { __hip_bfloat162 h; uint32_t u; } cv;
  cv.h = __float22bfloat162_rn(make_float2(a, b));
  return cv.u;
}

// ---------------- kernel 1: GroupNorm partial sums + weight bf16 conversion ----------------
// 1024 blocks = 64 (b,g) * 16 parts; each writes its own partial slot.
__global__ void k_gnstats(const float* __restrict__ x,
                          const float* __restrict__ wq, const float* __restrict__ wo,
                          u16* __restrict__ wq_bf, u16* __restrict__ wo_bf,
                          float* __restrict__ sraw) {
  int blk = blockIdx.x;                              // 1024 = 64 bg * 16 parts
  int bg = blk >> 4, part = blk & 15;
  const float4* p = (const float4*)(x + (size_t)bg * 36864) + part * 576;
  float s = 0.f, ss = 0.f;
  for (int i = threadIdx.x; i < 576; i += 256) {
    float4 v = p[i];
    s  += v.x + v.y + v.z + v.w;
    ss += v.x * v.x + v.y * v.y + v.z * v.z + v.w * v.w;
  }
  int lane = threadIdx.x & 63, wv = threadIdx.x >> 6;
  for (int m = 1; m < 64; m <<= 1) { s += __shfl_xor(s, m, 64); ss += __shfl_xor(ss, m, 64); }
  __shared__ float rs[4], rss[4];
  if (lane == 0) { rs[wv] = s; rss[wv] = ss; }
  __syncthreads();
  if (threadIdx.x == 0) {
    sraw[blk * 2]     = rs[0] + rs[1] + rs[2] + rs[3];
    sraw[blk * 2 + 1] = rss[0] + rss[1] + rss[2] + rss[3];
  }
  int gid = blk * 256 + threadIdx.x;                 // 262144 threads
  if (gid < 196608) wq_bf[gid] = f2bf(wq[gid]);
  if (gid < 65536)  wo_bf[gid] = f2bf(wo[gid]);
}

// ---------------- kernel 2: normalize + transpose-write normed^T [n][c] bf16 ----------------
__global__ void k_gnnorm(const float* __restrict__ x, const float* __restrict__ w,
                         const float* __restrict__ bias, const float* __restrict__ sraw,
                         u16* __restrict__ nt) {
  int bid = blockIdx.x;                              // 576 = 4b * 36sblk * 4cq
  int b = bid / 144, r = bid % 144;
  int sblk = r >> 2, cq = r & 3;
  int t = threadIdx.x;
  int ni = t & 63, cgrp = t >> 6;
  int s = sblk * 64 + ni;
  int cbase = cq * 64 + cgrp * 16;
  int bgi = b * 16 + (cbase >> 4);
  float sx = 0.f, ssx = 0.f;
  #pragma unroll
  for (int pp = 0; pp < 16; ++pp) {
    sx  += sraw[bgi * 32 + pp * 2];
    ssx += sraw[bgi * 32 + pp * 2 + 1];
  }
  float mean = sx * (1.f / 36864.f);
  float var  = ssx * (1.f / 36864.f) - mean * mean;
  float rstd = rsqrtf(var + 1e-5f);
  bf16x8 v0, v1;
  #pragma unroll
  for (int e = 0; e < 16; ++e) {
    int c = cbase + e;
    float val = x[(size_t)(b * 256 + c) * S + s];
    float xn = (val - mean) * rstd * w[c] + bias[c];
    if (e < 8) v0[e] = (short)f2bf(xn); else v1[e - 8] = (short)f2bf(xn);
  }
  u16* dst = nt + (size_t)(b * S + s) * 256 + cbase;
  *(bf16x8*)dst = v0;
  *(bf16x8*)(dst + 8) = v1;
}

// ---------------- kernel 3: QKV GEMM + fused transpose epilogue ----------------
// V columns stored PERMUTED within each 32-key group: key k=16a+4g+r -> pos 8g+4a+r.
__global__ __launch_bounds__(256) void k_qkv(const u16* __restrict__ A,
                                             const u16* __restrict__ Bm,
                                             u16* __restrict__ qkt,
                                             u16* __restrict__ vt) {
  __shared__ __align__(16) u16 As[2][64 * 32];
  __shared__ __align__(16) u16 Bs[2][128 * 32];
  int tid = threadIdx.x, lane = tid & 63, w = tid >> 6;
  int wr = w >> 1, wc = w & 1;
  int cb = lane & 15, q4 = lane >> 4;
  int m0 = blockIdx.y * 64, n0 = blockIdx.x * 128;

  const u16* gA0 = A  + (size_t)(m0 + (tid >> 2)) * 256 + (tid & 3) * 8;
  const u16* gB0 = Bm + (size_t)(n0 + (tid >> 2)) * 256 + (tid & 3) * 8;
  const u16* gB1 = gB0 + 64 * 256;
  char* lA = (char*)&As[0][0] + (w << 10);
  char* lB = (char*)&Bs[0][0] + (w << 10);

  #define STAGE_Q(buf, k0) do {                      \
    GLDS(gA0 + (k0), lA + (buf) * 4096);             \
    GLDS(gB0 + (k0), lB + (buf) * 8192);             \
    GLDS(gB1 + (k0), lB + (buf) * 8192 + 4096);      \
  } while (0)

  f32x4 zero4 = {0.f, 0.f, 0.f, 0.f};
  f32x4 acc[2][4];
  for (int i = 0; i < 2; ++i) for (int j = 0; j < 4; ++j) acc[i][j] = zero4;

  STAGE_Q(0, 0);
  __syncthreads();
  for (int ks = 0; ks < 8; ++ks) {
    int cur = ks & 1;
    if (ks < 7) STAGE_Q(cur ^ 1, (ks + 1) * 32);
    const u16* as = &As[cur][0];
    const u16* bs = &Bs[cur][0];
    bf16x8 af[2], bfr[4];
    for (int i = 0; i < 2; ++i)
      af[i]  = *(const bf16x8*)&as[(wr * 32 + i * 16 + cb) * 32 + 8 * q4];
    for (int j = 0; j < 4; ++j)
      bfr[j] = *(const bf16x8*)&bs[(wc * 64 + j * 16 + cb) * 32 + 8 * q4];
    for (int i = 0; i < 2; ++i)
      for (int j = 0; j < 4; ++j)
        acc[i][j] = __builtin_amdgcn_mfma_f32_16x16x32_bf16(af[i], bfr[j], acc[i][j], 0, 0, 0);
    __syncthreads();
  }

  for (int i = 0; i < 2; ++i)
    for (int j = 0; j < 4; ++j) {
      int ob = m0 + wr * 32 + i * 16 + q4 * 4;
      int n  = n0 + wc * 64 + j * 16 + cb;
      int h = ob / 96, oq = ob % 96;
      if (oq < 64) {
        float sc = (oq < 32) ? QS : 1.f;
        u16x4 pk;
        for (int r = 0; r < 4; ++r) pk[r] = f2bf(acc[i][j][r] * sc);
        *(u16x4*)&qkt[(size_t)n * 512 + h * 64 + oq] = pk;
      } else {
        int nk = n & 31;                             // key within 32-group: 16a+4g+r
        int np = (n & ~31) | ((((nk >> 2) & 3) << 3) + ((nk >> 4) << 2) + (nk & 3));
        for (int r = 0; r < 4; ++r)
          vt[(size_t)(h * 32 + oq - 64 + r) * 9216 + np] = f2bf(acc[i][j][r]);
      }
    }
  #undef STAGE_Q
}

// ---------------- kernel 4: flash attention, 64 q/wave ----------------
// 576 blocks x 4 waves = 2 q-subtiles (64 q each) x 2 key-halves.
// kf/vb loaded once per tile, shared across 4 qi streams (4-deep ILP covers
// reduced TLP). In-register permuted P; l via ones-MFMA; no-max softmax.
struct SMain { u16 Ks[2][2][2048]; u16 Vd[2][2][2048]; };   // [half][buf][...]
struct SComb { float O[4][2176]; float L[4][64]; };         // O: [32d][64q] stride 68
__global__ __launch_bounds__(256) void k_attn(const u16* __restrict__ qkt,
                                              const u16* __restrict__ vt,
                                              u16* __restrict__ ot) {
  __shared__ __align__(16) union { SMain s; SComb c; } lds;

  int tid = threadIdx.x, lane = tid & 63, w = tid >> 6;
  int cb = lane & 15, g4 = lane >> 4;
  int qw = w & 1, half = w >> 1;
  // XCD swizzle: 576 = 8 XCD * 72
  int hw = blockIdx.x;
  int orig = (hw & 7) * 72 + (hw >> 3);
  int bh = orig / 18, qtile = orig % 18;
  int b = bh >> 3, h = bh & 7;
  int q0 = qtile * 128 + qw * 64;                    // 64 q for this wave

  const u16* kbase = qkt + (size_t)(b * S) * 512 + h * 64 + 32 + (size_t)half * NKEYS * 512;
  const u16* vbase = vt + (size_t)(h * 32) * 9216 + (size_t)b * S + half * NKEYS;

  bf16x8 qf[4];
  #pragma unroll
  for (int qi = 0; qi < 4; ++qi)
    qf[qi] = *(const bf16x8*)&qkt[(size_t)(b * S + q0 + 16 * qi + cb) * 512 + h * 64 + 8 * g4];
  bf16x8 vones;
  #pragma unroll
  for (int e = 0; e < 8; ++e) vones[e] = (short)0x3F80;   // bf16 1.0

  f32x4 zero4 = {0.f, 0.f, 0.f, 0.f};
  f32x4 acc_o[4][2];
  #pragma unroll
  for (int qi = 0; qi < 4; ++qi) { acc_o[qi][0] = zero4; acc_o[qi][1] = zero4; }
  f32x4 lacc4[4];
  #pragma unroll
  for (int qi = 0; qi < 4; ++qi) lacc4[qi] = zero4;

  int xk = (cb ^ (cb >> 2)) & 3;

  // hoisted LDS read addresses (buf0; buf1 = +2048 u16 = 4096B)
  const u16* p_k = &lds.s.Ks[half][0][cb * 32 + ((g4 ^ xk) * 8)];      // k4: +512 u16
  const u16* p_v[2];                                                   // [kk]; jd: +1024 u16
  #pragma unroll
  for (int kk = 0; kk < 2; ++kk)
    p_v[kk] = &lds.s.Vd[half][0][cb * 64 + (((4 * kk + g4) ^ (cb & 7)) << 3)];

  // staging: 2 waves per half (ww = qw); each lane stages 2 chunks of each array
  int ww = qw;
  int c1 = ww * 64 + lane, c2 = c1 + 128;
  int kr1 = c1 >> 2, kc1 = (c1 & 3) ^ ((kr1 ^ (kr1 >> 2)) & 3);
  int kr2 = c2 >> 2, kc2 = (c2 & 3) ^ ((kr2 ^ (kr2 >> 2)) & 3);
  int vr1 = c1 >> 3, vc1 = (c1 & 7) ^ (vr1 & 7);
  int vr2 = c2 >> 3, vc2 = (c2 & 7) ^ (vr2 & 7);
  const u16* gK1 = kbase + (size_t)kr1 * 512 + kc1 * 8;
  const u16* gK2 = kbase + (size_t)kr2 * 512 + kc2 * 8;
  const u16* gV1 = vbase + (size_t)vr1 * 9216 + vc1 * 8;
  const u16* gV2 = vbase + (size_t)vr2 * 9216 + vc2 * 8;
  char* ldsK = (char*)&lds.s.Ks[half][0][0] + (ww << 10);
  char* ldsV = (char*)&lds.s.Vd[half][0][0] + (ww << 10);

  #define STAGE_A(buf) do {                          \
    GLDS(gK1, ldsK + (buf) * 4096);                  \
    GLDS(gK2, ldsK + (buf) * 4096 + 2048);           \
    GLDS(gV1, ldsV + (buf) * 4096);                  \
    GLDS(gV2, ldsV + (buf) * 4096 + 2048);           \
    gK1 += 64 * 512; gK2 += 64 * 512;                \
    gV1 += 64; gV2 += 64;                            \
  } while (0)

  #define TILE(buf, pf) do {                                                   \
    if (pf) STAGE_A(buf ^ 1);                                                  \
    bf16x8 kf[4];                                                              \
    _Pragma("unroll")                                                          \
    for (int k4 = 0; k4 < 4; ++k4)                                             \
      kf[k4] = *(const bf16x8*)(p_k + (buf) * 2048 + k4 * 512);                \
    bf16x8 vb[2][2];  /* [jd][kk], shared by all qi */                         \
    _Pragma("unroll")                                                          \
    for (int jd = 0; jd < 2; ++jd)                                             \
      _Pragma("unroll")                                                        \
      for (int kk = 0; kk < 2; ++kk)                                           \
        vb[jd][kk] = *(const bf16x8*)(p_v[kk] + (buf) * 2048 + jd * 1024);     \
    _Pragma("unroll")                                                          \
    for (int qi = 0; qi < 4; ++qi) {                                           \
      f32x4 pacc[4];                                                           \
      __builtin_amdgcn_s_setprio(1);                                           \
      _Pragma("unroll")                                                        \
      for (int k4 = 0; k4 < 4; ++k4)                                           \
        pacc[k4] = __builtin_amdgcn_mfma_f32_16x16x32_bf16(kf[k4], qf[qi], zero4, 0, 0, 0); \
      __builtin_amdgcn_s_setprio(0);                                           \
      uint32_t W01[4], W23[4];                                                 \
      _Pragma("unroll")                                                        \
      for (int k4 = 0; k4 < 4; ++k4) {                                         \
        f32x4 p = pacc[k4];                                                    \
        float e0 = __builtin_amdgcn_exp2f(p[0]);                               \
        float e1 = __builtin_amdgcn_exp2f(p[1]);                               \
        float e2 = __builtin_amdgcn_exp2f(p[2]);                               \
        float e3 = __builtin_amdgcn_exp2f(p[3]);                               \
        W01[k4] = pk_bf16(e0, e1);                                             \
        W23[k4] = pk_bf16(e2, e3);                                             \
      }                                                                        \
      union { u32x4 u; bf16x8 v; } pu0, pu1;                                   \
      pu0.u = (u32x4){W01[0], W23[0], W01[1], W23[1]};                         \
      pu1.u = (u32x4){W01[2], W23[2], W01[3], W23[3]};                         \
      __builtin_amdgcn_s_setprio(1);                                           \
      lacc4[qi] = __builtin_amdgcn_mfma_f32_16x16x32_bf16(pu0.v, vones, lacc4[qi], 0, 0, 0); \
      lacc4[qi] = __builtin_amdgcn_mfma_f32_16x16x32_bf16(pu1.v, vones, lacc4[qi], 0, 0, 0); \
      _Pragma("unroll")                                                        \
      for (int jd = 0; jd < 2; ++jd) {                                         \
        acc_o[qi][jd] = __builtin_amdgcn_mfma_f32_16x16x32_bf16(pu0.v, vb[jd][0], acc_o[qi][jd], 0, 0, 0); \
        acc_o[qi][jd] = __builtin_amdgcn_mfma_f32_16x16x32_bf16(pu1.v, vb[jd][1], acc_o[qi][jd], 0, 0, 0); \
      }                                                                        \
      __builtin_amdgcn_s_setprio(0);                                           \
    }                                                                          \
    __syncthreads();                                                           \
  } while (0)

  STAGE_A(0);
  __syncthreads();
  for (int it = 0; it < 9; ++it) {                   // 18 tiles per half, unroll x2
    TILE(0, 1);
    TILE(1, it < 8);
  }

  // ---- in-block split-K combine (scratch overlays dead Ks/Vd via union) ----
  // region reg = qw*2+half: [32 d][64 q] f32, row stride 68 (pad vs conflicts).
  int reg = qw * 2 + half;
  float* myO = lds.c.O[reg];
  #pragma unroll
  for (int qi = 0; qi < 4; ++qi)
    #pragma unroll
    for (int jd = 0; jd < 2; ++jd)
      *(f32x4*)&myO[(cb + 16 * jd) * 68 + 16 * qi + 4 * g4] = acc_o[qi][jd];
  if (cb == 0) {
    #pragma unroll
    for (int qi = 0; qi < 4; ++qi)
      *(f32x4*)&lds.c.L[reg][16 * qi + 4 * g4] = lacc4[qi];
  }
  __syncthreads();

  // wave (qw, half) outputs q-subtile qw, d-range [half*16, half*16+16)
  const float* A0 = lds.c.O[qw * 2];
  const float* A1 = lds.c.O[qw * 2 + 1];
  int dd = half * 16 + cb;
  #pragma unroll
  for (int qi2 = 0; qi2 < 4; ++qi2) {
    f32x4 s0 = *(const f32x4*)&A0[dd * 68 + 16 * qi2 + 4 * g4];
    f32x4 s1 = *(const f32x4*)&A1[dd * 68 + 16 * qi2 + 4 * g4];
    f32x4 lt0 = *(const f32x4*)&lds.c.L[qw * 2][16 * qi2 + 4 * g4];
    f32x4 lt1 = *(const f32x4*)&lds.c.L[qw * 2 + 1][16 * qi2 + 4 * g4];
    #pragma unroll
    for (int r = 0; r < 4; ++r) {
      float inv = __builtin_amdgcn_rcpf(lt0[r] + lt1[r]);
      int sq = q0 + 16 * qi2 + 4 * g4 + r;
      ot[(size_t)(b * S + sq) * 256 + h * 32 + dd] = f2bf((s0[r] + s1[r]) * inv);
    }
  }
  #undef STAGE_A
  #undef TILE
}

// ---------------- kernel 5: out projection + bias + residual ----------------
__global__ __launch_bounds__(256) void k_oproj(const u16* __restrict__ A,
                                               const u16* __restrict__ Bm,
                                               float* __restrict__ out,
                                               const float* __restrict__ bias,
                                               const float* __restrict__ resid) {
  __shared__ __align__(16) u16 As[2][64 * 32];
  __shared__ __align__(16) u16 Bs[2][64 * 32];
  int tid = threadIdx.x, lane = tid & 63, w = tid >> 6;
  int cb = lane & 15, q4 = lane >> 4;
  int m0 = blockIdx.y * 64, n0 = blockIdx.x * 64;

  const u16* gA0 = A  + (size_t)(m0 + (tid >> 2)) * 256 + (tid & 3) * 8;
  const u16* gB0 = Bm + (size_t)(n0 + (tid >> 2)) * 256 + (tid & 3) * 8;
  char* lA = (char*)&As[0][0] + (w << 10);
  char* lB = (char*)&Bs[0][0] + (w << 10);

  #define STAGE_O(buf, k0) do {                      \
    GLDS(gA0 + (k0), lA + (buf) * 4096);             \
    GLDS(gB0 + (k0), lB + (buf) * 4096);             \
  } while (0)

  f32x4 zero4 = {0.f, 0.f, 0.f, 0.f};
  f32x4 acc[4];
  for (int j = 0; j < 4; ++j) acc[j] = zero4;

  STAGE_O(0, 0);
  __syncthreads();
  for (int ks = 0; ks < 8; ++ks) {
    int cur = ks & 1;
    if (ks < 7) STAGE_O(cur ^ 1, (ks + 1) * 32);
    const u16* as = &As[cur][0];
    const u16* bs = &Bs[cur][0];
    bf16x8 af = *(const bf16x8*)&as[(w * 16 + cb) * 32 + 8 * q4];
    bf16x8 bfr[4];
    for (int j = 0; j < 4; ++j)
      bfr[j] = *(const bf16x8*)&bs[(j * 16 + cb) * 32 + 8 * q4];
    for (int j = 0; j < 4; ++j)
      acc[j] = __builtin_amdgcn_mfma_f32_16x16x32_bf16(af, bfr[j], acc[j], 0, 0, 0);
    __syncthreads();
  }

  for (int j = 0; j < 4; ++j)
    for (int r = 0; r < 4; ++r) {
      int o = m0 + w * 16 + q4 * 4 + r;
      int n = n0 + j * 16 + cb;
      int b = n / S, s2 = n % S;
      size_t gi = (size_t)(b * 256 + o) * S + s2;
      out[gi] = acc[j][r] + bias[o] + resid[gi];
    }
  #undef STAGE_O
}

// ---------------- host launch ----------------
extern "C" void kernel_launch(void* const* d_in, const int* in_sizes, int n_in,
                              void* d_out, int out_size, void* d_ws, size_t ws_size,
                              hipStream_t stream) {
  const float* input = (const float*)d_in[0];
  const float* gnw   = (const float*)d_in[1];
  const float* gnb   = (const float*)d_in[2];
  const float* wqkv  = (const float*)d_in[3];
  const float* wout  = (const float*)d_in[4];
  const float* bout  = (const float*)d_in[5];
  float* out = (float*)d_out;
  char* ws = (char*)d_ws;

  size_t o_wq  = 0;                                   // 768*256*2
  size_t o_wo  = o_wq + (size_t)768 * 256 * 2;        // 256*256*2
  size_t o_st  = o_wo + (size_t)256 * 256 * 2;        // partial stats (8KB)
  size_t o_nt  = o_st + 8192;                         // 9216*256*2 (nt; reused as ot)
  size_t o_qkt = o_nt + (size_t)9216 * 256 * 2;       // 9216*512*2
  size_t o_vt  = o_qkt + (size_t)9216 * 512 * 2;      // 256*9216*2

  u16*    wq_bf = (u16*)(ws + o_wq);
  u16*    wo_bf = (u16*)(ws + o_wo);
  float*  sraw  = (float*)(ws + o_st);
  u16*    nt    = (u16*)(ws + o_nt);
  u16*    qkt   = (u16*)(ws + o_qkt);
  u16*    vt    = (u16*)(ws + o_vt);
  u16*    otb   = (u16*)(ws + o_nt);                  // reuse nt region (dead after k_qkv)

  k_gnstats<<<1024, 256, 0, stream>>>(input, wqkv, wout, wq_bf, wo_bf, sraw);
  k_gnnorm<<<576, 256, 0, stream>>>(input, gnw, gnb, sraw, nt);
  k_qkv<<<dim3(72, 12), 256, 0, stream>>>(wq_bf, nt, qkt, vt);
  k_attn<<<576, 256, 0, stream>>>(qkt, vt, otb);
  k_oproj<<<dim3(144, 4), 256, 0, stream>>>(wo_bf, otb, out, bout, input);
}

// Round 15
// 77.183 us; speedup vs baseline: 1.1866x; 1.1866x over previous
//
#include <hip/hip_runtime.h>
#include <hip/hip_bf16.h>
#include <stdint.h>

#define S    2304
#define CHN  256
#define BATCH 4
#define NKEYS 1152                  // keys per half (in-block 2-way split)
#define QS   0.09016844005556021f   // (1/16) * log2(e)

typedef __attribute__((ext_vector_type(8))) short bf16x8;
typedef __attribute__((ext_vector_type(4))) short bf16x4;
typedef __attribute__((ext_vector_type(4))) float f32x4;
typedef __attribute__((ext_vector_type(4))) uint32_t u32x4;
typedef __attribute__((ext_vector_type(4))) unsigned short u16x4;
typedef unsigned short u16;

#define AS1 __attribute__((address_space(1)))
#define AS3 __attribute__((address_space(3)))
#define GLDS(gptr, lptr) __builtin_amdgcn_global_load_lds((const AS1 void*)(gptr), (AS3 void*)(lptr), 16, 0, 0)

__device__ __forceinline__ u16 f2bf(float f) {
  union { float f; uint32_t u; } v; v.f = f;
  uint32_t u = v.u;
  u += 0x7fffu + ((u >> 16) & 1u);
  return (u16)(u >> 16);
}
__device__ __forceinline__ float bf2f(u16 h) {
  union { uint32_t u; float f; } v; v.u = ((uint32_t)h) << 16;
  return v.f;
}
__device__ __forceinline__ uint32_t pk_bf16(float a, float b) {
  union { __hip_bfloat162 h; uint32_t u; } cv;
  cv.h = __float22bfloat162_rn(make_float2(a, b));
  return cv.u;
}

// ---------------- kernel 1: GroupNorm partial sums + weight bf16 conversion ----------------
// 1024 blocks = 64 (b,g) * 16 parts; each writes its own partial slot.
__global__ void k_gnstats(const float* __restrict__ x,
                          const float* __restrict__ wq, const float* __restrict__ wo,
                          u16* __restrict__ wq_bf, u16* __restrict__ wo_bf,
                          float* __restrict__ sraw) {
  int blk = blockIdx.x;                              // 1024 = 64 bg * 16 parts
  int bg = blk >> 4, part = blk & 15;
  const float4* p = (const float4*)(x + (size_t)bg * 36864) + part * 576;
  float s = 0.f, ss = 0.f;
  for (int i = threadIdx.x; i < 576; i += 256) {
    float4 v = p[i];
    s  += v.x + v.y + v.z + v.w;
    ss += v.x * v.x + v.y * v.y + v.z * v.z + v.w * v.w;
  }
  int lane = threadIdx.x & 63, wv = threadIdx.x >> 6;
  for (int m = 1; m < 64; m <<= 1) { s += __shfl_xor(s, m, 64); ss += __shfl_xor(ss, m, 64); }
  __shared__ float rs[4], rss[4];
  if (lane == 0) { rs[wv] = s; rss[wv] = ss; }
  __syncthreads();
  if (threadIdx.x == 0) {
    sraw[blk * 2]     = rs[0] + rs[1] + rs[2] + rs[3];
    sraw[blk * 2 + 1] = rss[0] + rss[1] + rss[2] + rss[3];
  }
  int gid = blk * 256 + threadIdx.x;                 // 262144 threads
  if (gid < 196608) wq_bf[gid] = f2bf(wq[gid]);
  if (gid < 65536)  wo_bf[gid] = f2bf(wo[gid]);
}

// ---------------- kernel 2: normalize + transpose-write normed^T [n][c] bf16 ----------------
__global__ void k_gnnorm(const float* __restrict__ x, const float* __restrict__ w,
                         const float* __restrict__ bias, const float* __restrict__ sraw,
                         u16* __restrict__ nt) {
  int bid = blockIdx.x;                              // 576 = 4b * 36sblk * 4cq
  int b = bid / 144, r = bid % 144;
  int sblk = r >> 2, cq = r & 3;
  int t = threadIdx.x;
  int ni = t & 63, cgrp = t >> 6;
  int s = sblk * 64 + ni;
  int cbase = cq * 64 + cgrp * 16;
  int bgi = b * 16 + (cbase >> 4);
  float sx = 0.f, ssx = 0.f;
  #pragma unroll
  for (int pp = 0; pp < 16; ++pp) {
    sx  += sraw[bgi * 32 + pp * 2];
    ssx += sraw[bgi * 32 + pp * 2 + 1];
  }
  float mean = sx * (1.f / 36864.f);
  float var  = ssx * (1.f / 36864.f) - mean * mean;
  float rstd = rsqrtf(var + 1e-5f);
  bf16x8 v0, v1;
  #pragma unroll
  for (int e = 0; e < 16; ++e) {
    int c = cbase + e;
    float val = x[(size_t)(b * 256 + c) * S + s];
    float xn = (val - mean) * rstd * w[c] + bias[c];
    if (e < 8) v0[e] = (short)f2bf(xn); else v1[e - 8] = (short)f2bf(xn);
  }
  u16* dst = nt + (size_t)(b * S + s) * 256 + cbase;
  *(bf16x8*)dst = v0;
  *(bf16x8*)(dst + 8) = v1;
}

// ---------------- kernel 3: QKV GEMM + fused transpose epilogue ----------------
// V columns stored PERMUTED within each 32-key group: key k=16a+4g+r -> pos 8g+4a+r,
// so attention's PV fragments are single contiguous 16B runs.
__global__ __launch_bounds__(256) void k_qkv(const u16* __restrict__ A,
                                             const u16* __restrict__ Bm,
                                             u16* __restrict__ qkt,
                                             u16* __restrict__ vt) {
  __shared__ __align__(16) u16 As[2][64 * 32];
  __shared__ __align__(16) u16 Bs[2][128 * 32];
  int tid = threadIdx.x, lane = tid & 63, w = tid >> 6;
  int wr = w >> 1, wc = w & 1;
  int cb = lane & 15, q4 = lane >> 4;
  int m0 = blockIdx.y * 64, n0 = blockIdx.x * 128;

  const u16* gA0 = A  + (size_t)(m0 + (tid >> 2)) * 256 + (tid & 3) * 8;
  const u16* gB0 = Bm + (size_t)(n0 + (tid >> 2)) * 256 + (tid & 3) * 8;
  const u16* gB1 = gB0 + 64 * 256;
  char* lA = (char*)&As[0][0] + (w << 10);
  char* lB = (char*)&Bs[0][0] + (w << 10);

  #define STAGE_Q(buf, k0) do {                      \
    GLDS(gA0 + (k0), lA + (buf) * 4096);             \
    GLDS(gB0 + (k0), lB + (buf) * 8192);             \
    GLDS(gB1 + (k0), lB + (buf) * 8192 + 4096);      \
  } while (0)

  f32x4 zero4 = {0.f, 0.f, 0.f, 0.f};
  f32x4 acc[2][4];
  for (int i = 0; i < 2; ++i) for (int j = 0; j < 4; ++j) acc[i][j] = zero4;

  STAGE_Q(0, 0);
  __syncthreads();
  for (int ks = 0; ks < 8; ++ks) {
    int cur = ks & 1;
    if (ks < 7) STAGE_Q(cur ^ 1, (ks + 1) * 32);
    const u16* as = &As[cur][0];
    const u16* bs = &Bs[cur][0];
    bf16x8 af[2], bfr[4];
    for (int i = 0; i < 2; ++i)
      af[i]  = *(const bf16x8*)&as[(wr * 32 + i * 16 + cb) * 32 + 8 * q4];
    for (int j = 0; j < 4; ++j)
      bfr[j] = *(const bf16x8*)&bs[(wc * 64 + j * 16 + cb) * 32 + 8 * q4];
    for (int i = 0; i < 2; ++i)
      for (int j = 0; j < 4; ++j)
        acc[i][j] = __builtin_amdgcn_mfma_f32_16x16x32_bf16(af[i], bfr[j], acc[i][j], 0, 0, 0);
    __syncthreads();
  }

  for (int i = 0; i < 2; ++i)
    for (int j = 0; j < 4; ++j) {
      int ob = m0 + wr * 32 + i * 16 + q4 * 4;
      int n  = n0 + wc * 64 + j * 16 + cb;
      int h = ob / 96, oq = ob % 96;
      if (oq < 64) {
        float sc = (oq < 32) ? QS : 1.f;
        u16x4 pk;
        for (int r = 0; r < 4; ++r) pk[r] = f2bf(acc[i][j][r] * sc);
        *(u16x4*)&qkt[(size_t)n * 512 + h * 64 + oq] = pk;
      } else {
        int nk = n & 31;                             // key within 32-group: 16a+4g+r
        int np = (n & ~31) | ((((nk >> 2) & 3) << 3) + ((nk >> 4) << 2) + (nk & 3));
        for (int r = 0; r < 4; ++r)
          vt[(size_t)(h * 32 + oq - 64 + r) * 9216 + np] = f2bf(acc[i][j][r]);
      }
    }
  #undef STAGE_Q
}

// ---------------- kernel 4: flash attention, 32 q/wave, b128 V reads, 32KB LDS ----------------
// R13-proven: 256 threads = 4 waves = 2 q-subtiles (32 q) x 2 key-halves.
// kf/vb loaded once per tile, shared by both qi. V perm baked into vt layout.
// LDS exactly 32KB -> 5 blocks/CU -> 1152 blocks in one round.
__global__ __launch_bounds__(256, 4) void k_attn(const u16* __restrict__ qkt,
                                                 const u16* __restrict__ vt,
                                                 u16* __restrict__ ot) {
  __shared__ __align__(16) u16 Ks[2][2][2048];       // [half][buf][64key*32d] swizzled
  __shared__ __align__(16) u16 Vd[2][2][2048];       // [half][buf][32d*64key] perm+swizzled

  int tid = threadIdx.x, lane = tid & 63, w = tid >> 6;
  int cb = lane & 15, g4 = lane >> 4;
  int qw = w & 1, half = w >> 1;
  // XCD swizzle: 1152 = 8 XCD * 144
  int hw = blockIdx.x;
  int orig = (hw & 7) * 144 + (hw >> 3);
  int bh = orig / 36, qtile = orig % 36;
  int b = bh >> 3, h = bh & 7;
  int q0 = qtile * 64 + qw * 32;                     // 32 q for this wave

  const u16* kbase = qkt + (size_t)(b * S) * 512 + h * 64 + 32 + (size_t)half * NKEYS * 512;
  const u16* vbase = vt + (size_t)(h * 32) * 9216 + (size_t)b * S + half * NKEYS;

  bf16x8 qf[2];
  #pragma unroll
  for (int qi = 0; qi < 2; ++qi)
    qf[qi] = *(const bf16x8*)&qkt[(size_t)(b * S + q0 + 16 * qi + cb) * 512 + h * 64 + 8 * g4];
  bf16x8 vones;
  #pragma unroll
  for (int e = 0; e < 8; ++e) vones[e] = (short)0x3F80;   // bf16 1.0

  f32x4 zero4 = {0.f, 0.f, 0.f, 0.f};
  f32x4 acc_o[2][2];
  acc_o[0][0] = zero4; acc_o[0][1] = zero4; acc_o[1][0] = zero4; acc_o[1][1] = zero4;
  f32x4 lacc4[2]; lacc4[0] = zero4; lacc4[1] = zero4;

  int xk = (cb ^ (cb >> 2)) & 3;

  // hoisted LDS read addresses (buf0; buf1 = +2048 u16 = 4096B)
  const u16* p_k = &Ks[half][0][cb * 32 + ((g4 ^ xk) * 8)];            // k4: +512 u16
  const u16* p_v[2];                                                   // [kk]; jd: +1024 u16
  #pragma unroll
  for (int kk = 0; kk < 2; ++kk)
    p_v[kk] = &Vd[half][0][cb * 64 + (((4 * kk + g4) ^ (cb & 7)) << 3)];

  // staging: 2 waves per half; each lane stages 2 chunks of each array
  int ww = w & 1;                                    // wave index within the half
  int c1 = ww * 64 + lane, c2 = c1 + 128;
  int kr1 = c1 >> 2, kc1 = (c1 & 3) ^ ((kr1 ^ (kr1 >> 2)) & 3);
  int kr2 = c2 >> 2, kc2 = (c2 & 3) ^ ((kr2 ^ (kr2 >> 2)) & 3);
  int vr1 = c1 >> 3, vc1 = (c1 & 7) ^ (vr1 & 7);
  int vr2 = c2 >> 3, vc2 = (c2 & 7) ^ (vr2 & 7);
  const u16* gK1 = kbase + (size_t)kr1 * 512 + kc1 * 8;
  const u16* gK2 = kbase + (size_t)kr2 * 512 + kc2 * 8;
  const u16* gV1 = vbase + (size_t)vr1 * 9216 + vc1 * 8;
  const u16* gV2 = vbase + (size_t)vr2 * 9216 + vc2 * 8;
  char* ldsK = (char*)&Ks[half][0][0] + (ww << 10);
  char* ldsV = (char*)&Vd[half][0][0] + (ww << 10);

  #define STAGE_A(buf) do {                          \
    GLDS(gK1, ldsK + (buf) * 4096);                  \
    GLDS(gK2, ldsK + (buf) * 4096 + 2048);           \
    GLDS(gV1, ldsV + (buf) * 4096);                  \
    GLDS(gV2, ldsV + (buf) * 4096 + 2048);           \
    gK1 += 64 * 512; gK2 += 64 * 512;                \
    gV1 += 64; gV2 += 64;                            \
  } while (0)

  #define TILE(buf, pf) do {                                                   \
    if (pf) STAGE_A(buf ^ 1);                                                  \
    bf16x8 kf[4];                                                              \
    _Pragma("unroll")                                                          \
    for (int k4 = 0; k4 < 4; ++k4)                                             \
      kf[k4] = *(const bf16x8*)(p_k + (buf) * 2048 + k4 * 512);                \
    bf16x8 vb[2][2];  /* [jd][kk], shared by both qi */                        \
    _Pragma("unroll")                                                          \
    for (int jd = 0; jd < 2; ++jd)                                             \
      _Pragma("unroll")                                                        \
      for (int kk = 0; kk < 2; ++kk)                                           \
        vb[jd][kk] = *(const bf16x8*)(p_v[kk] + (buf) * 2048 + jd * 1024);     \
    _Pragma("unroll")                                                          \
    for (int qi = 0; qi < 2; ++qi) {                                           \
      f32x4 pacc[4];                                                           \
      __builtin_amdgcn_s_setprio(1);                                           \
      _Pragma("unroll")                                                        \
      for (int k4 = 0; k4 < 4; ++k4)                                           \
        pacc[k4] = __builtin_amdgcn_mfma_f32_16x16x32_bf16(kf[k4], qf[qi], zero4, 0, 0, 0); \
      __builtin_amdgcn_s_setprio(0);                                           \
      uint32_t W01[4], W23[4];                                                 \
      _Pragma("unroll")                                                        \
      for (int k4 = 0; k4 < 4; ++k4) {                                         \
        f32x4 p = pacc[k4];                                                    \
        float e0 = __builtin_amdgcn_exp2f(p[0]);                               \
        float e1 = __builtin_amdgcn_exp2f(p[1]);                               \
        float e2 = __builtin_amdgcn_exp2f(p[2]);                               \
        float e3 = __builtin_amdgcn_exp2f(p[3]);                               \
        W01[k4] = pk_bf16(e0, e1);                                             \
        W23[k4] = pk_bf16(e2, e3);                                             \
      }                                                                        \
      union { u32x4 u; bf16x8 v; } pu0, pu1;                                   \
      pu0.u = (u32x4){W01[0], W23[0], W01[1], W23[1]};                         \
      pu1.u = (u32x4){W01[2], W23[2], W01[3], W23[3]};                         \
      __builtin_amdgcn_s_setprio(1);                                           \
      lacc4[qi] = __builtin_amdgcn_mfma_f32_16x16x32_bf16(pu0.v, vones, lacc4[qi], 0, 0, 0); \
      lacc4[qi] = __builtin_amdgcn_mfma_f32_16x16x32_bf16(pu1.v, vones, lacc4[qi], 0, 0, 0); \
      _Pragma("unroll")                                                        \
      for (int jd = 0; jd < 2; ++jd) {                                         \
        acc_o[qi][jd] = __builtin_amdgcn_mfma_f32_16x16x32_bf16(pu0.v, vb[jd][0], acc_o[qi][jd], 0, 0, 0); \
        acc_o[qi][jd] = __builtin_amdgcn_mfma_f32_16x16x32_bf16(pu1.v, vb[jd][1], acc_o[qi][jd], 0, 0, 0); \
      }                                                                        \
      __builtin_amdgcn_s_setprio(0);                                           \
    }                                                                          \
    __syncthreads();                                                           \
  } while (0)

  STAGE_A(0);
  __syncthreads();
  for (int it = 0; it < 9; ++it) {                   // 18 tiles per half, unroll x2
    TILE(0, 1);
    TILE(1, it < 8);
  }

  // ---- in-block split-K combine (scratch overlays dead Ks/Vd; l in Ks tail) ----
  // region reg = qw*2+half: 32q x 32d f32, d-row stride 36 (pad vs conflicts).
  // regions 0,1 in Ks (f32 offsets 0,1152); 2,3 in Vd; Ls at Ks f32 offset 3072.
  float* scrK = (float*)&Ks[0][0][0];
  float* scrV = (float*)&Vd[0][0][0];
  float* LsF  = scrK + 3072;                         // [qw][half][q32] = qw*64+half*32+q
  int reg = qw * 2 + half;
  float* myS = (reg < 2 ? scrK : scrV) + (reg & 1) * 1152;
  #pragma unroll
  for (int qi = 0; qi < 2; ++qi)
    #pragma unroll
    for (int jd = 0; jd < 2; ++jd)
      *(f32x4*)&myS[(cb + 16 * jd) * 36 + 16 * qi + 4 * g4] = acc_o[qi][jd];
  if (cb == 0) {
    *(f32x4*)&LsF[qw * 64 + half * 32 + 4 * g4] = lacc4[0];
    *(f32x4*)&LsF[qw * 64 + half * 32 + 16 + 4 * g4] = lacc4[1];
  }
  __syncthreads();

  // wave (qw, half) outputs q-subtile qw, d-range [half*16, half*16+16)
  const float* s0p = (qw == 0 ? scrK : scrV);
  const float* s1p = s0p + 1152;
  int dd = half * 16 + cb;
  #pragma unroll
  for (int qi2 = 0; qi2 < 2; ++qi2) {
    f32x4 s0 = *(const f32x4*)&s0p[dd * 36 + 16 * qi2 + 4 * g4];
    f32x4 s1 = *(const f32x4*)&s1p[dd * 36 + 16 * qi2 + 4 * g4];
    f32x4 lt0 = *(const f32x4*)&LsF[qw * 64 + 16 * qi2 + 4 * g4];
    f32x4 lt1 = *(const f32x4*)&LsF[qw * 64 + 32 + 16 * qi2 + 4 * g4];
    #pragma unroll
    for (int r = 0; r < 4; ++r) {
      float inv = __builtin_amdgcn_rcpf(lt0[r] + lt1[r]);
      int sq = q0 + 16 * qi2 + 4 * g4 + r;
      ot[(size_t)(b * S + sq) * 256 + h * 32 + dd] = f2bf((s0[r] + s1[r]) * inv);
    }
  }
  #undef STAGE_A
  #undef TILE
}

// ---------------- kernel 5: out projection + bias + residual ----------------
__global__ __launch_bounds__(256) void k_oproj(const u16* __restrict__ A,
                                               const u16* __restrict__ Bm,
                                               float* __restrict__ out,
                                               const float* __restrict__ bias,
                                               const float* __restrict__ resid) {
  __shared__ __align__(16) u16 As[2][64 * 32];
  __shared__ __align__(16) u16 Bs[2][64 * 32];
  int tid = threadIdx.x, lane = tid & 63, w = tid >> 6;
  int cb = lane & 15, q4 = lane >> 4;
  int m0 = blockIdx.y * 64, n0 = blockIdx.x * 64;

  const u16* gA0 = A  + (size_t)(m0 + (tid >> 2)) * 256 + (tid & 3) * 8;
  const u16* gB0 = Bm + (size_t)(n0 + (tid >> 2)) * 256 + (tid & 3) * 8;
  char* lA = (char*)&As[0][0] + (w << 10);
  char* lB = (char*)&Bs[0][0] + (w << 10);

  #define STAGE_O(buf, k0) do {                      \
    GLDS(gA0 + (k0), lA + (buf) * 4096);             \
    GLDS(gB0 + (k0), lB + (buf) * 4096);             \
  } while (0)

  f32x4 zero4 = {0.f, 0.f, 0.f, 0.f};
  f32x4 acc[4];
  for (int j = 0; j < 4; ++j) acc[j] = zero4;

  STAGE_O(0, 0);
  __syncthreads();
  for (int ks = 0; ks < 8; ++ks) {
    int cur = ks & 1;
    if (ks < 7) STAGE_O(cur ^ 1, (ks + 1) * 32);
    const u16* as = &As[cur][0];
    const u16* bs = &Bs[cur][0];
    bf16x8 af = *(const bf16x8*)&as[(w * 16 + cb) * 32 + 8 * q4];
    bf16x8 bfr[4];
    for (int j = 0; j < 4; ++j)
      bfr[j] = *(const bf16x8*)&bs[(j * 16 + cb) * 32 + 8 * q4];
    for (int j = 0; j < 4; ++j)
      acc[j] = __builtin_amdgcn_mfma_f32_16x16x32_bf16(af, bfr[j], acc[j], 0, 0, 0);
    __syncthreads();
  }

  for (int j = 0; j < 4; ++j)
    for (int r = 0; r < 4; ++r) {
      int o = m0 + w * 16 + q4 * 4 + r;
      int n = n0 + j * 16 + cb;
      int b = n / S, s2 = n % S;
      size_t gi = (size_t)(b * 256 + o) * S + s2;
      out[gi] = acc[j][r] + bias[o] + resid[gi];
    }
  #undef STAGE_O
}

// ---------------- host launch ----------------
extern "C" void kernel_launch(void* const* d_in, const int* in_sizes, int n_in,
                              void* d_out, int out_size, void* d_ws, size_t ws_size,
                              hipStream_t stream) {
  const float* input = (const float*)d_in[0];
  const float* gnw   = (const float*)d_in[1];
  const float* gnb   = (const float*)d_in[2];
  const float* wqkv  = (const float*)d_in[3];
  const float* wout  = (const float*)d_in[4];
  const float* bout  = (const float*)d_in[5];
  float* out = (float*)d_out;
  char* ws = (char*)d_ws;

  size_t o_wq  = 0;                                   // 768*256*2
  size_t o_wo  = o_wq + (size_t)768 * 256 * 2;        // 256*256*2
  size_t o_st  = o_wo + (size_t)256 * 256 * 2;        // partial stats (8KB)
  size_t o_nt  = o_st + 8192;                         // 9216*256*2 (nt; reused as ot)
  size_t o_qkt = o_nt + (size_t)9216 * 256 * 2;       // 9216*512*2
  size_t o_vt  = o_qkt + (size_t)9216 * 512 * 2;      // 256*9216*2

  u16*    wq_bf = (u16*)(ws + o_wq);
  u16*    wo_bf = (u16*)(ws + o_wo);
  float*  sraw  = (float*)(ws + o_st);
  u16*    nt    = (u16*)(ws + o_nt);
  u16*    qkt   = (u16*)(ws + o_qkt);
  u16*    vt    = (u16*)(ws + o_vt);
  u16*    otb   = (u16*)(ws + o_nt);                  // reuse nt region (dead after k_qkv)

  k_gnstats<<<1024, 256, 0, stream>>>(input, wqkv, wout, wq_bf, wo_bf, sraw);
  k_gnnorm<<<576, 256, 0, stream>>>(input, gnw, gnb, sraw, nt);
  k_qkv<<<dim3(72, 12), 256, 0, stream>>>(wq_bf, nt, qkt, vt);
  k_attn<<<1152, 256, 0, stream>>>(qkt, vt, otb);
  k_oproj<<<dim3(144, 4), 256, 0, stream>>>(wo_bf, otb, out, bout, input);
}